// Round 1
// 527.992 us; speedup vs baseline: 1.0375x; 1.0375x over previous
//
#include <hip/hip_runtime.h>
#include <hip/hip_bf16.h>

#define S_LEN 2048
#define HDIM 3584
#define NH 28
#define NKV 4
#define HD 128
#define NQD 3584   // NH*HD
#define NKVD 512   // NKV*HD
#define NQKV 4608  // NQD + 2*NKVD

typedef __bf16 bf16x8 __attribute__((ext_vector_type(8)));
typedef float f32x4 __attribute__((ext_vector_type(4)));
typedef unsigned short u16x8 __attribute__((ext_vector_type(8)));

__device__ __forceinline__ unsigned short f2bf(float f) {
  unsigned u = __builtin_bit_cast(unsigned, f);
  u += 0x7fffu + ((u >> 16) & 1u);   // RNE
  return (unsigned short)(u >> 16);
}

__device__ __forceinline__ bf16x8 ld_frag(const unsigned short* p) {
  union { u16x8 u; bf16x8 b; } cv;
  cv.u = *(const u16x8*)p;   // 16B ds_read_b128
  return cv.b;
}

// async global->LDS, 16B per lane; lds dest is wave-uniform base + lane*16
__device__ __forceinline__ void async_cp16(const void* g, void* lds) {
  __builtin_amdgcn_global_load_lds(
      (const __attribute__((address_space(1))) unsigned int*)g,
      (__attribute__((address_space(3))) unsigned int*)lds, 16, 0, 0);
}

// ---------------- fp32 -> bf16 flat convert ----------------
__global__ __launch_bounds__(256) void cvt_kernel(const float* __restrict__ in,
                                                  unsigned short* __restrict__ out, int n4) {
  int i = blockIdx.x * 256 + threadIdx.x;
  if (i >= n4) return;
  float4 v = ((const float4*)in)[i];
  ushort4 o;
  o.x = f2bf(v.x); o.y = f2bf(v.y); o.z = f2bf(v.z); o.w = f2bf(v.w);
  ((ushort4*)out)[i] = o;
}

// ---------------- tiled transpose + fp32->bf16: out[c][r] = in[r][c] ----------------
__global__ __launch_bounds__(256) void tcvt(const float* __restrict__ in,
                                            unsigned short* __restrict__ out,
                                            int R, int C, int ldin) {
  __shared__ float t[32][33];
  const int tx = threadIdx.x, ty = threadIdx.y;   // 32 x 8
  const int r0 = blockIdx.y * 32, c0 = blockIdx.x * 32;
#pragma unroll
  for (int j = 0; j < 4; ++j)
    t[ty + 8 * j][tx] = in[(size_t)(r0 + ty + 8 * j) * ldin + c0 + tx];
  __syncthreads();
#pragma unroll
  for (int j = 0; j < 4; ++j)
    out[(size_t)(c0 + ty + 8 * j) * R + r0 + tx] = f2bf(t[tx][ty + 8 * j]);
}

// ---------------- concat bias [bq | bk | bv] ----------------
__global__ void biascat(const float* __restrict__ bq, const float* __restrict__ bk,
                        const float* __restrict__ bv, float* __restrict__ o) {
  int i = blockIdx.x * 256 + threadIdx.x;
  if (i < NQD) o[i] = bq[i];
  else if (i < NQD + NKVD) o[i] = bk[i - NQD];
  else if (i < NQKV) o[i] = bv[i - NQD - NKVD];
}

// ---------------- build mrope'd cos/sin, transposed: cmT[d][s] ----------------
// sections: [0,16)=0 [16,40)=1 [40,64)=2 [64,80)=0 [80,104)=1 [104,128)=2
__global__ void mrope_build(const float* __restrict__ cosp, const float* __restrict__ sinp,
                            float* __restrict__ cmT, float* __restrict__ smT) {
  const int d = blockIdx.y;
  const int s = blockIdx.x * 256 + threadIdx.x;
  const int sec = d < 16 ? 0 : d < 40 ? 1 : d < 64 ? 2 : d < 80 ? 0 : d < 104 ? 1 : 2;
  const size_t src = ((size_t)sec * S_LEN + s) * HD + d;
  cmT[(size_t)d * S_LEN + s] = cosp[src];
  smT[(size_t)d * S_LEN + s] = sinp[src];
}

// ---------------- 128x128 bf16 GEMM, BK=64, global_load_lds staging ----------------
// Wave owns rows [wrow, wrow+64) and cols {wc2+0..31} U {wc2+64..95} (closed under ^64
// so the rope partner d^64 is register j^2 in the same lane).
// LDS chunk swizzle: position (row,p) holds logical k-chunk p^(row&7) -> 2-way max.
// MODE 0: fp32 C out (+bias). MODE 1: fused QKV epilogue (rope q/k, transpose-cast v).
#define QSCALE (0.08838834764831845f * 1.4426950408889634f)
template <int MODE>
__global__ __launch_bounds__(256) void gemm_k64(
    const unsigned short* __restrict__ A,   // [M][K] bf16
    const unsigned short* __restrict__ Bt,  // [N][K] bf16
    const float* __restrict__ bias,         // [N] or null
    const float* __restrict__ cmT,          // [HD][S] (MODE 1)
    const float* __restrict__ smT,
    float* __restrict__ Cout,               // MODE 0
    unsigned short* __restrict__ qr,        // MODE 1: [NH][S][HD]
    unsigned short* __restrict__ kr,        // MODE 1: [NKV][S][HD]
    unsigned short* __restrict__ vt,        // MODE 1: [NKVD][S]
    int M, int N, int K) {
  __shared__ __align__(16) unsigned short As[128 * 64];
  __shared__ __align__(16) unsigned short Bs[128 * 64];
  const int tid = threadIdx.x, wave = tid >> 6;
  const int lane = tid & 63, quad = lane >> 4, l16 = lane & 15;
  const int bm = blockIdx.y * 128, bn = blockIdx.x * 128;
  const int wrow = (wave >> 1) * 64, wc2 = (wave & 1) * 32;
  f32x4 acc[4][4] = {};
  for (int k0 = 0; k0 < K; k0 += 64) {
#pragma unroll
    for (int t = 0; t < 4; ++t) {
      int g = t * 256 + tid;                 // chunk 0..1023
      int row = g >> 3;
      int c = (g & 7) ^ (row & 7);           // logical k-chunk to fetch
      async_cp16(&A[(size_t)(bm + row) * K + k0 + c * 8], &As[(size_t)g * 8]);
      async_cp16(&Bt[(size_t)(bn + row) * K + k0 + c * 8], &Bs[(size_t)g * 8]);
    }
    __syncthreads();
    bf16x8 af[4][2], bfr[4][2];
#pragma unroll
    for (int i = 0; i < 4; ++i) {
      int ra = wrow + i * 16 + l16;
#pragma unroll
      for (int ks = 0; ks < 2; ++ks)
        af[i][ks] = ld_frag(&As[ra * 64 + (((ks * 4 + quad) ^ (ra & 7)) << 3)]);
    }
#pragma unroll
    for (int j = 0; j < 4; ++j) {
      int rb = wc2 + (j & 1) * 16 + (j >> 1) * 64 + l16;
#pragma unroll
      for (int ks = 0; ks < 2; ++ks)
        bfr[j][ks] = ld_frag(&Bs[rb * 64 + (((ks * 4 + quad) ^ (rb & 7)) << 3)]);
    }
#pragma unroll
    for (int ks = 0; ks < 2; ++ks)
#pragma unroll
      for (int i = 0; i < 4; ++i)
#pragma unroll
        for (int j = 0; j < 4; ++j)
          acc[i][j] = __builtin_amdgcn_mfma_f32_16x16x32_bf16(af[i][ks], bfr[j][ks],
                                                              acc[i][j], 0, 0, 0);
    __syncthreads();
  }
  int dcol[4];
  float bj[4];
#pragma unroll
  for (int j = 0; j < 4; ++j) {
    dcol[j] = wc2 + (j & 1) * 16 + (j >> 1) * 64 + l16;
    bj[j] = bias ? bias[bn + dcol[j]] : 0.f;
  }
  if (MODE == 0) {
#pragma unroll
    for (int i = 0; i < 4; ++i) {
      int row0 = bm + wrow + i * 16 + quad * 4;
#pragma unroll
      for (int j = 0; j < 4; ++j)
#pragma unroll
        for (int r = 0; r < 4; ++r)
          Cout[(size_t)(row0 + r) * N + bn + dcol[j]] = acc[i][j][r] + bj[j];
    }
  } else {
    const int tile = blockIdx.x;  // 0..27 q head | 28..31 k head | 32..35 v head
    if (tile < 32) {
      const bool isq = tile < 28;
      unsigned short* dst = isq ? (qr + (size_t)tile * S_LEN * HD)
                                : (kr + (size_t)(tile - 28) * S_LEN * HD);
      const float scl = isq ? QSCALE : 1.0f;
#pragma unroll
      for (int i = 0; i < 4; ++i) {
        int srow = bm + wrow + i * 16 + quad * 4;
#pragma unroll
        for (int j = 0; j < 4; ++j) {
          int d = dcol[j];
          f32x4 cm4 = *(const f32x4*)&cmT[(size_t)d * S_LEN + srow];
          f32x4 sm4 = *(const f32x4*)&smT[(size_t)d * S_LEN + srow];
#pragma unroll
          for (int r = 0; r < 4; ++r) {
            float x = acc[i][j][r] + bj[j];
            float px = acc[i][j ^ 2][r] + bj[j ^ 2];
            float pr = (j < 2) ? -px : px;   // rotate_half partner (d^64, same lane)
            dst[(size_t)(srow + r) * HD + d] = f2bf((x * cm4[r] + pr * sm4[r]) * scl);
          }
        }
      }
    } else {
      const int kvh = tile - 32;
#pragma unroll
      for (int i = 0; i < 4; ++i) {
        int srow = bm + wrow + i * 16 + quad * 4;
#pragma unroll
        for (int j = 0; j < 4; ++j) {
          int d = dcol[j];
          unsigned w0 = (unsigned)f2bf(acc[i][j][0] + bj[j]) |
                        ((unsigned)f2bf(acc[i][j][1] + bj[j]) << 16);
          unsigned w1 = (unsigned)f2bf(acc[i][j][2] + bj[j]) |
                        ((unsigned)f2bf(acc[i][j][3] + bj[j]) << 16);
          unsigned short* vp = &vt[(size_t)(kvh * HD + d) * S_LEN + srow];
          *(unsigned*)vp = w0;
          *(unsigned*)(vp + 2) = w1;
        }
      }
    }
  }
}

// ---------------- flash attention, S^T formulation, tile-0 max ----------------
// block = (head, 64 q rows); 4 waves x 16-q strips. Q in registers (B-operand).
// S^T = K.Q^T : C col=l16=q, row=quad*4+r=sk_local. Tile-0 row max (scores bounded;
// overflow would be inf -> loud fail). P truncated to bf16 (RTZ); lsum sums the
// SAME truncated values so num/denom errors cancel. No accO rescale.
// v2: double-buffered K/V staging (prefetch kt+1 during compute of kt) — removes
// the per-iter vmcnt(0)-drain-before-compute stall; one barrier per iter.
// s_setprio(1) wraps both MFMA clusters (T5: pays once waves have role diversity).
__global__ __launch_bounds__(256) void attn2(
    const unsigned short* __restrict__ Q,   // [NH][S][HD] bf16, pre-scaled by QSCALE
    const unsigned short* __restrict__ Kh,  // [NKV][S][HD] bf16
    const unsigned short* __restrict__ Vt,  // [NKVD][S] bf16 (d-major)
    unsigned short* __restrict__ O) {       // [S][NQD] bf16
  __shared__ __align__(16) unsigned short Ks[2][64 * 128];
  __shared__ __align__(16) unsigned short Vs[2][128 * 64];
  const int tid = threadIdx.x, wave = tid >> 6, lane = tid & 63;
  const int quad = lane >> 4, l16 = lane & 15;
  const int b = blockIdx.x;
  const int xcd = b & 7, slot = b >> 3;
  const int kvh = xcd & 3;
  const int strip = (xcd >> 2) * 112 + slot;
  const int h = kvh * 7 + (strip >> 5);
  const int qt = strip & 31;

  const unsigned short* Kbase = Kh + (size_t)kvh * S_LEN * HD;
  const unsigned short* Vbase = Vt + (size_t)kvh * HD * S_LEN;

  auto stage = [&](int bsel, int kt) {
#pragma unroll
    for (int t = 0; t < 4; ++t) {
      int g = (wave * 4 + t) * 64 + lane;
      int krow = g >> 4, kq = ((g & 15) ^ (krow & 15)) * 8;
      async_cp16(&Kbase[(size_t)(kt * 64 + krow) * HD + kq], &Ks[bsel][(size_t)g * 8]);
      int vrow = g >> 3, vc = ((g & 7) ^ (vrow & 7)) * 8;
      async_cp16(&Vbase[(size_t)vrow * S_LEN + kt * 64 + vc], &Vs[bsel][(size_t)g * 8]);
    }
  };

  stage(0, 0);                 // tile 0 in flight while Q fragments load
  bf16x8 qf[4];
  const size_t qrow = ((size_t)h * S_LEN + qt * 64 + wave * 16 + l16) * HD;
#pragma unroll
  for (int kc = 0; kc < 4; ++kc)
    qf[kc] = ld_frag(&Q[qrow + kc * 32 + quad * 8]);
  f32x4 accO[8] = {};
  float m = 0.f, lsum = 0.f;
  __syncthreads();             // implicit vmcnt(0): tile 0 landed
  int cur = 0;
  for (int kt = 0; kt < S_LEN / 64; ++kt) {
    if (kt + 1 < S_LEN / 64) stage(cur ^ 1, kt + 1);   // prefetch next tile
    const unsigned short* ksb = Ks[cur];
    const unsigned short* vsb = Vs[cur];
    f32x4 st[4] = {};
    __builtin_amdgcn_s_setprio(1);
#pragma unroll
    for (int s4 = 0; s4 < 4; ++s4) {
      int row = s4 * 16 + l16;
#pragma unroll
      for (int kc = 0; kc < 4; ++kc) {
        bf16x8 a = ld_frag(&ksb[row * 128 + (((kc * 4 + quad) ^ (row & 15)) << 3)]);
        st[s4] = __builtin_amdgcn_mfma_f32_16x16x32_bf16(a, qf[kc], st[s4], 0, 0, 0);
      }
    }
    __builtin_amdgcn_s_setprio(0);
    if (kt == 0) {   // per-q-row max of tile 0; never updated (scores bounded)
      float mt = st[0][0];
#pragma unroll
      for (int s4 = 0; s4 < 4; ++s4)
#pragma unroll
        for (int r = 0; r < 4; ++r) mt = fmaxf(mt, st[s4][r]);
      mt = fmaxf(mt, __shfl_xor(mt, 16));
      mt = fmaxf(mt, __shfl_xor(mt, 32));
      m = mt;
    }
    float sum = 0.f;
    unsigned pk[4][2];
#pragma unroll
    for (int s4 = 0; s4 < 4; ++s4) {
      unsigned u0 = __builtin_bit_cast(unsigned, exp2f(st[s4][0] - m)) & 0xffff0000u;
      unsigned u1 = __builtin_bit_cast(unsigned, exp2f(st[s4][1] - m)) & 0xffff0000u;
      unsigned u2 = __builtin_bit_cast(unsigned, exp2f(st[s4][2] - m)) & 0xffff0000u;
      unsigned u3 = __builtin_bit_cast(unsigned, exp2f(st[s4][3] - m)) & 0xffff0000u;
      sum += __builtin_bit_cast(float, u0) + __builtin_bit_cast(float, u1) +
             __builtin_bit_cast(float, u2) + __builtin_bit_cast(float, u3);
      pk[s4][0] = (u0 >> 16) | u1;
      pk[s4][1] = (u2 >> 16) | u3;
    }
    sum += __shfl_xor(sum, 16);
    sum += __shfl_xor(sum, 32);
    lsum += sum;
    // channel shuffles (src pushes uniform tile c; dest selects c = 2ks+(quad>>1))
    const int src0 = ((quad & 1) * 2) * 16 + l16;
    const int src1 = src0 + 16;
    unsigned sh[4][4];
#pragma unroll
    for (int c = 0; c < 4; ++c) {
      sh[c][0] = (unsigned)__shfl((int)pk[c][0], src0);
      sh[c][1] = (unsigned)__shfl((int)pk[c][1], src0);
      sh[c][2] = (unsigned)__shfl((int)pk[c][0], src1);
      sh[c][3] = (unsigned)__shfl((int)pk[c][1], src1);
    }
    const bool hi = (quad >> 1) != 0;
    bf16x8 pb[2];
#pragma unroll
    for (int ks2 = 0; ks2 < 2; ++ks2) {
      union { unsigned u[4]; bf16x8 bv; } cv;
#pragma unroll
      for (int w = 0; w < 4; ++w)
        cv.u[w] = hi ? sh[2 * ks2 + 1][w] : sh[2 * ks2][w];
      pb[ks2] = cv.bv;
    }
    __builtin_amdgcn_s_setprio(1);
#pragma unroll
    for (int dt = 0; dt < 8; ++dt) {
      int row = dt * 16 + l16;
#pragma unroll
      for (int ks2 = 0; ks2 < 2; ++ks2) {
        bf16x8 a = ld_frag(&vsb[row * 64 + (((ks2 * 4 + quad) ^ (row & 7)) << 3)]);
        accO[dt] = __builtin_amdgcn_mfma_f32_16x16x32_bf16(a, pb[ks2], accO[dt], 0, 0, 0);
      }
    }
    __builtin_amdgcn_s_setprio(0);
    __syncthreads();   // implicit vmcnt(0): prefetch landed; all reads of buf[cur] done
    cur ^= 1;
  }
  float rl = 1.f / lsum;
  const size_t orow = ((size_t)(qt * 64 + wave * 16 + l16)) * NQD + h * HD;
#pragma unroll
  for (int dt = 0; dt < 8; ++dt) {
    unsigned w0 = (unsigned)f2bf(accO[dt][0] * rl) | ((unsigned)f2bf(accO[dt][1] * rl) << 16);
    unsigned w1 = (unsigned)f2bf(accO[dt][2] * rl) | ((unsigned)f2bf(accO[dt][3] * rl) << 16);
    *(unsigned*)&O[orow + dt * 16 + quad * 4] = w0;
    *(unsigned*)&O[orow + dt * 16 + quad * 4 + 2] = w1;
  }
}

extern "C" void kernel_launch(void* const* d_in, const int* in_sizes, int n_in,
                              void* d_out, int out_size, void* d_ws, size_t ws_size,
                              hipStream_t stream) {
  const float* hidden = (const float*)d_in[0];
  const float* cosp = (const float*)d_in[1];
  const float* sinp = (const float*)d_in[2];
  const float* Wq = (const float*)d_in[3];
  const float* bq = (const float*)d_in[4];
  const float* Wk = (const float*)d_in[5];
  const float* bk = (const float*)d_in[6];
  const float* Wv = (const float*)d_in[7];
  const float* bv = (const float*)d_in[8];
  const float* Wo = (const float*)d_in[9];
  float* out = (float*)d_out;

  const size_t HID_N = (size_t)S_LEN * HDIM;
  const size_t WQ_N = (size_t)HDIM * NQD;
  const size_t KV_N = (size_t)S_LEN * NKVD;

  char* p = (char*)d_ws;
  size_t off = 0;
  auto take = [&](size_t bytes) {
    void* r = p + off; off += (bytes + 255) & ~(size_t)255; return r;
  };
  unsigned short* hid_bf = (unsigned short*)take(HID_N * 2);
  unsigned short* wqkvT = (unsigned short*)take((size_t)NQKV * HDIM * 2);
  unsigned short* woT = (unsigned short*)take(WQ_N * 2);
  float* bcat = (float*)take(NQKV * 4);
  float* cmT = (float*)take((size_t)HD * S_LEN * 4);
  float* smT = (float*)take((size_t)HD * S_LEN * 4);
  unsigned short* q_rot = (unsigned short*)take(HID_N * 2);
  unsigned short* k_rot = (unsigned short*)take(KV_N * 2);
  unsigned short* v_t = (unsigned short*)take(KV_N * 2);
  unsigned short* attn_bf = (unsigned short*)take(HID_N * 2);
  if (off > ws_size) return;   // loud failure: output stays poisoned

  cvt_kernel<<<(int)((HID_N / 4 + 255) / 256), 256, 0, stream>>>(hidden, hid_bf, (int)(HID_N / 4));
  dim3 tb(32, 8);
  tcvt<<<dim3(NQD / 32, HDIM / 32), tb, 0, stream>>>(Wq, wqkvT, HDIM, NQD, NQD);
  tcvt<<<dim3(NKVD / 32, HDIM / 32), tb, 0, stream>>>(Wk, wqkvT + (size_t)NQD * HDIM, HDIM, NKVD, NKVD);
  tcvt<<<dim3(NKVD / 32, HDIM / 32), tb, 0, stream>>>(Wv, wqkvT + (size_t)(NQD + NKVD) * HDIM, HDIM, NKVD, NKVD);
  tcvt<<<dim3(NQD / 32, NQD / 32), tb, 0, stream>>>(Wo, woT, NQD, NQD, NQD);
  biascat<<<(NQKV + 255) / 256, 256, 0, stream>>>(bq, bk, bv, bcat);
  mrope_build<<<dim3(S_LEN / 256, HD), 256, 0, stream>>>(cosp, sinp, cmT, smT);

  // fused QKV projection + rope + head-major/transposed stores
  gemm_k64<1><<<dim3(NQKV / 128, S_LEN / 128), 256, 0, stream>>>(
      hid_bf, wqkvT, bcat, cmT, smT, nullptr, q_rot, k_rot, v_t, S_LEN, NQKV, HDIM);
  // attention
  attn2<<<NH * (S_LEN / 64), 256, 0, stream>>>(q_rot, k_rot, v_t, attn_bf);
  // output projection
  gemm_k64<0><<<dim3(NQD / 128, S_LEN / 128), 256, 0, stream>>>(
      attn_bf, woT, nullptr, nullptr, nullptr, out, nullptr, nullptr, nullptr,
      S_LEN, NQD, NQD);
}

// Round 2
// 480.595 us; speedup vs baseline: 1.1398x; 1.0986x over previous
//
#include <hip/hip_runtime.h>
#include <hip/hip_bf16.h>

#define S_LEN 2048
#define HDIM 3584
#define NH 28
#define NKV 4
#define HD 128
#define NQD 3584   // NH*HD
#define NKVD 512   // NKV*HD
#define NQKV 4608  // NQD + 2*NKVD

typedef __bf16 bf16x8 __attribute__((ext_vector_type(8)));
typedef float f32x4 __attribute__((ext_vector_type(4)));
typedef unsigned short u16x8 __attribute__((ext_vector_type(8)));

__device__ __forceinline__ unsigned short f2bf(float f) {
  unsigned u = __builtin_bit_cast(unsigned, f);
  u += 0x7fffu + ((u >> 16) & 1u);   // RNE
  return (unsigned short)(u >> 16);
}

__device__ __forceinline__ bf16x8 ld_frag(const unsigned short* p) {
  union { u16x8 u; bf16x8 b; } cv;
  cv.u = *(const u16x8*)p;   // 16B ds_read_b128
  return cv.b;
}

// async global->LDS, 16B per lane; lds dest is wave-uniform base + lane*16
__device__ __forceinline__ void async_cp16(const void* g, void* lds) {
  __builtin_amdgcn_global_load_lds(
      (const __attribute__((address_space(1))) unsigned int*)g,
      (__attribute__((address_space(3))) unsigned int*)lds, 16, 0, 0);
}

// ---------------- fp32 -> bf16 flat convert ----------------
__global__ __launch_bounds__(256) void cvt_kernel(const float* __restrict__ in,
                                                  unsigned short* __restrict__ out, int n4) {
  int i = blockIdx.x * 256 + threadIdx.x;
  if (i >= n4) return;
  float4 v = ((const float4*)in)[i];
  ushort4 o;
  o.x = f2bf(v.x); o.y = f2bf(v.y); o.z = f2bf(v.z); o.w = f2bf(v.w);
  ((ushort4*)out)[i] = o;
}

// ---------------- tiled transpose + fp32->bf16: out[c][r] = in[r][c] ----------------
__global__ __launch_bounds__(256) void tcvt(const float* __restrict__ in,
                                            unsigned short* __restrict__ out,
                                            int R, int C, int ldin) {
  __shared__ float t[32][33];
  const int tx = threadIdx.x, ty = threadIdx.y;   // 32 x 8
  const int r0 = blockIdx.y * 32, c0 = blockIdx.x * 32;
#pragma unroll
  for (int j = 0; j < 4; ++j)
    t[ty + 8 * j][tx] = in[(size_t)(r0 + ty + 8 * j) * ldin + c0 + tx];
  __syncthreads();
#pragma unroll
  for (int j = 0; j < 4; ++j)
    out[(size_t)(c0 + ty + 8 * j) * R + r0 + tx] = f2bf(t[tx][ty + 8 * j]);
}

// ---------------- concat bias [bq | bk | bv] ----------------
__global__ void biascat(const float* __restrict__ bq, const float* __restrict__ bk,
                        const float* __restrict__ bv, float* __restrict__ o) {
  int i = blockIdx.x * 256 + threadIdx.x;
  if (i < NQD) o[i] = bq[i];
  else if (i < NQD + NKVD) o[i] = bk[i - NQD];
  else if (i < NQKV) o[i] = bv[i - NQD - NKVD];
}

// ---------------- build mrope'd cos/sin, transposed: cmT[d][s] ----------------
// sections: [0,16)=0 [16,40)=1 [40,64)=2 [64,80)=0 [80,104)=1 [104,128)=2
__global__ void mrope_build(const float* __restrict__ cosp, const float* __restrict__ sinp,
                            float* __restrict__ cmT, float* __restrict__ smT) {
  const int d = blockIdx.y;
  const int s = blockIdx.x * 256 + threadIdx.x;
  const int sec = d < 16 ? 0 : d < 40 ? 1 : d < 64 ? 2 : d < 80 ? 0 : d < 104 ? 1 : 2;
  const size_t src = ((size_t)sec * S_LEN + s) * HD + d;
  cmT[(size_t)d * S_LEN + s] = cosp[src];
  smT[(size_t)d * S_LEN + s] = sinp[src];
}

// ---------------- 128x128 bf16 GEMM, BK=64, global_load_lds staging ----------------
// Wave owns rows [wrow, wrow+64) and cols {wc2+0..31} U {wc2+64..95} (closed under ^64
// so the rope partner d^64 is register j^2 in the same lane).
// LDS chunk swizzle: position (row,p) holds logical k-chunk p^(row&7) -> 2-way max.
// v2: double-buffered LDS, prefetch tile k+1 before computing tile k — one barrier
// per K-step, vmcnt(0) drain lands after the MFMA cluster instead of before it.
// MODE 0: fp32 C out (+bias). MODE 1: fused QKV epilogue (rope q/k, transpose-cast v).
#define QSCALE (0.08838834764831845f * 1.4426950408889634f)
template <int MODE>
__global__ __launch_bounds__(256) void gemm_k64(
    const unsigned short* __restrict__ A,   // [M][K] bf16
    const unsigned short* __restrict__ Bt,  // [N][K] bf16
    const float* __restrict__ bias,         // [N] or null
    const float* __restrict__ cmT,          // [HD][S] (MODE 1)
    const float* __restrict__ smT,
    float* __restrict__ Cout,               // MODE 0
    unsigned short* __restrict__ qr,        // MODE 1: [NH][S][HD]
    unsigned short* __restrict__ kr,        // MODE 1: [NKV][S][HD]
    unsigned short* __restrict__ vt,        // MODE 1: [NKVD][S]
    int M, int N, int K) {
  __shared__ __align__(16) unsigned short As[2][128 * 64];
  __shared__ __align__(16) unsigned short Bs[2][128 * 64];
  const int tid = threadIdx.x, wave = tid >> 6;
  const int lane = tid & 63, quad = lane >> 4, l16 = lane & 15;
  const int bm = blockIdx.y * 128, bn = blockIdx.x * 128;
  const int wrow = (wave >> 1) * 64, wc2 = (wave & 1) * 32;
  f32x4 acc[4][4] = {};

  auto stage = [&](int bsel, int k0) {
#pragma unroll
    for (int t = 0; t < 4; ++t) {
      int g = t * 256 + tid;                 // chunk 0..1023
      int row = g >> 3;
      int c = (g & 7) ^ (row & 7);           // logical k-chunk to fetch
      async_cp16(&A[(size_t)(bm + row) * K + k0 + c * 8], &As[bsel][(size_t)g * 8]);
      async_cp16(&Bt[(size_t)(bn + row) * K + k0 + c * 8], &Bs[bsel][(size_t)g * 8]);
    }
  };

  stage(0, 0);
  __syncthreads();             // implicit vmcnt(0): tile 0 landed
  int cur = 0;
  for (int k0 = 0; k0 < K; k0 += 64) {
    if (k0 + 64 < K) stage(cur ^ 1, k0 + 64);   // prefetch next K-tile
    const unsigned short* as = As[cur];
    const unsigned short* bs = Bs[cur];
    bf16x8 af[4][2], bfr[4][2];
#pragma unroll
    for (int i = 0; i < 4; ++i) {
      int ra = wrow + i * 16 + l16;
#pragma unroll
      for (int ks = 0; ks < 2; ++ks)
        af[i][ks] = ld_frag(&as[ra * 64 + (((ks * 4 + quad) ^ (ra & 7)) << 3)]);
    }
#pragma unroll
    for (int j = 0; j < 4; ++j) {
      int rb = wc2 + (j & 1) * 16 + (j >> 1) * 64 + l16;
#pragma unroll
      for (int ks = 0; ks < 2; ++ks)
        bfr[j][ks] = ld_frag(&bs[rb * 64 + (((ks * 4 + quad) ^ (rb & 7)) << 3)]);
    }
    __builtin_amdgcn_s_setprio(1);
#pragma unroll
    for (int ks = 0; ks < 2; ++ks)
#pragma unroll
      for (int i = 0; i < 4; ++i)
#pragma unroll
        for (int j = 0; j < 4; ++j)
          acc[i][j] = __builtin_amdgcn_mfma_f32_16x16x32_bf16(af[i][ks], bfr[j][ks],
                                                              acc[i][j], 0, 0, 0);
    __builtin_amdgcn_s_setprio(0);
    __syncthreads();   // implicit vmcnt(0): prefetch landed; reads of buf[cur] retired
    cur ^= 1;
  }
  int dcol[4];
  float bj[4];
#pragma unroll
  for (int j = 0; j < 4; ++j) {
    dcol[j] = wc2 + (j & 1) * 16 + (j >> 1) * 64 + l16;
    bj[j] = bias ? bias[bn + dcol[j]] : 0.f;
  }
  if (MODE == 0) {
#pragma unroll
    for (int i = 0; i < 4; ++i) {
      int row0 = bm + wrow + i * 16 + quad * 4;
#pragma unroll
      for (int j = 0; j < 4; ++j)
#pragma unroll
        for (int r = 0; r < 4; ++r)
          Cout[(size_t)(row0 + r) * N + bn + dcol[j]] = acc[i][j][r] + bj[j];
    }
  } else {
    const int tile = blockIdx.x;  // 0..27 q head | 28..31 k head | 32..35 v head
    if (tile < 32) {
      const bool isq = tile < 28;
      unsigned short* dst = isq ? (qr + (size_t)tile * S_LEN * HD)
                                : (kr + (size_t)(tile - 28) * S_LEN * HD);
      const float scl = isq ? QSCALE : 1.0f;
#pragma unroll
      for (int i = 0; i < 4; ++i) {
        int srow = bm + wrow + i * 16 + quad * 4;
#pragma unroll
        for (int j = 0; j < 4; ++j) {
          int d = dcol[j];
          f32x4 cm4 = *(const f32x4*)&cmT[(size_t)d * S_LEN + srow];
          f32x4 sm4 = *(const f32x4*)&smT[(size_t)d * S_LEN + srow];
#pragma unroll
          for (int r = 0; r < 4; ++r) {
            float x = acc[i][j][r] + bj[j];
            float px = acc[i][j ^ 2][r] + bj[j ^ 2];
            float pr = (j < 2) ? -px : px;   // rotate_half partner (d^64, same lane)
            dst[(size_t)(srow + r) * HD + d] = f2bf((x * cm4[r] + pr * sm4[r]) * scl);
          }
        }
      }
    } else {
      const int kvh = tile - 32;
#pragma unroll
      for (int i = 0; i < 4; ++i) {
        int srow = bm + wrow + i * 16 + quad * 4;
#pragma unroll
        for (int j = 0; j < 4; ++j) {
          int d = dcol[j];
          unsigned w0 = (unsigned)f2bf(acc[i][j][0] + bj[j]) |
                        ((unsigned)f2bf(acc[i][j][1] + bj[j]) << 16);
          unsigned w1 = (unsigned)f2bf(acc[i][j][2] + bj[j]) |
                        ((unsigned)f2bf(acc[i][j][3] + bj[j]) << 16);
          unsigned short* vp = &vt[(size_t)(kvh * HD + d) * S_LEN + srow];
          *(unsigned*)vp = w0;
          *(unsigned*)(vp + 2) = w1;
        }
      }
    }
  }
}

// ---------------- flash attention, S^T formulation, tile-0 max ----------------
// block = (head, 64 q rows); 4 waves x 16-q strips. Q in registers (B-operand).
// S^T = K.Q^T : C col=l16=q, row=quad*4+r=sk_local. Tile-0 row max (scores bounded;
// overflow would be inf -> loud fail). P truncated to bf16 (RTZ); lsum sums the
// SAME truncated values so num/denom errors cancel. No accO rescale.
// v2: double-buffered K/V staging (prefetch kt+1 during compute of kt) — removes
// the per-iter vmcnt(0)-drain-before-compute stall; one barrier per iter.
// s_setprio(1) wraps both MFMA clusters (T5: pays once waves have role diversity).
__global__ __launch_bounds__(256) void attn2(
    const unsigned short* __restrict__ Q,   // [NH][S][HD] bf16, pre-scaled by QSCALE
    const unsigned short* __restrict__ Kh,  // [NKV][S][HD] bf16
    const unsigned short* __restrict__ Vt,  // [NKVD][S] bf16 (d-major)
    unsigned short* __restrict__ O) {       // [S][NQD] bf16
  __shared__ __align__(16) unsigned short Ks[2][64 * 128];
  __shared__ __align__(16) unsigned short Vs[2][128 * 64];
  const int tid = threadIdx.x, wave = tid >> 6, lane = tid & 63;
  const int quad = lane >> 4, l16 = lane & 15;
  const int b = blockIdx.x;
  const int xcd = b & 7, slot = b >> 3;
  const int kvh = xcd & 3;
  const int strip = (xcd >> 2) * 112 + slot;
  const int h = kvh * 7 + (strip >> 5);
  const int qt = strip & 31;

  const unsigned short* Kbase = Kh + (size_t)kvh * S_LEN * HD;
  const unsigned short* Vbase = Vt + (size_t)kvh * HD * S_LEN;

  auto stage = [&](int bsel, int kt) {
#pragma unroll
    for (int t = 0; t < 4; ++t) {
      int g = (wave * 4 + t) * 64 + lane;
      int krow = g >> 4, kq = ((g & 15) ^ (krow & 15)) * 8;
      async_cp16(&Kbase[(size_t)(kt * 64 + krow) * HD + kq], &Ks[bsel][(size_t)g * 8]);
      int vrow = g >> 3, vc = ((g & 7) ^ (vrow & 7)) * 8;
      async_cp16(&Vbase[(size_t)vrow * S_LEN + kt * 64 + vc], &Vs[bsel][(size_t)g * 8]);
    }
  };

  stage(0, 0);                 // tile 0 in flight while Q fragments load
  bf16x8 qf[4];
  const size_t qrow = ((size_t)h * S_LEN + qt * 64 + wave * 16 + l16) * HD;
#pragma unroll
  for (int kc = 0; kc < 4; ++kc)
    qf[kc] = ld_frag(&Q[qrow + kc * 32 + quad * 8]);
  f32x4 accO[8] = {};
  float m = 0.f, lsum = 0.f;
  __syncthreads();             // implicit vmcnt(0): tile 0 landed
  int cur = 0;
  for (int kt = 0; kt < S_LEN / 64; ++kt) {
    if (kt + 1 < S_LEN / 64) stage(cur ^ 1, kt + 1);   // prefetch next tile
    const unsigned short* ksb = Ks[cur];
    const unsigned short* vsb = Vs[cur];
    f32x4 st[4] = {};
    __builtin_amdgcn_s_setprio(1);
#pragma unroll
    for (int s4 = 0; s4 < 4; ++s4) {
      int row = s4 * 16 + l16;
#pragma unroll
      for (int kc = 0; kc < 4; ++kc) {
        bf16x8 a = ld_frag(&ksb[row * 128 + (((kc * 4 + quad) ^ (row & 15)) << 3)]);
        st[s4] = __builtin_amdgcn_mfma_f32_16x16x32_bf16(a, qf[kc], st[s4], 0, 0, 0);
      }
    }
    __builtin_amdgcn_s_setprio(0);
    if (kt == 0) {   // per-q-row max of tile 0; never updated (scores bounded)
      float mt = st[0][0];
#pragma unroll
      for (int s4 = 0; s4 < 4; ++s4)
#pragma unroll
        for (int r = 0; r < 4; ++r) mt = fmaxf(mt, st[s4][r]);
      mt = fmaxf(mt, __shfl_xor(mt, 16));
      mt = fmaxf(mt, __shfl_xor(mt, 32));
      m = mt;
    }
    float sum = 0.f;
    unsigned pk[4][2];
#pragma unroll
    for (int s4 = 0; s4 < 4; ++s4) {
      unsigned u0 = __builtin_bit_cast(unsigned, exp2f(st[s4][0] - m)) & 0xffff0000u;
      unsigned u1 = __builtin_bit_cast(unsigned, exp2f(st[s4][1] - m)) & 0xffff0000u;
      unsigned u2 = __builtin_bit_cast(unsigned, exp2f(st[s4][2] - m)) & 0xffff0000u;
      unsigned u3 = __builtin_bit_cast(unsigned, exp2f(st[s4][3] - m)) & 0xffff0000u;
      sum += __builtin_bit_cast(float, u0) + __builtin_bit_cast(float, u1) +
             __builtin_bit_cast(float, u2) + __builtin_bit_cast(float, u3);
      pk[s4][0] = (u0 >> 16) | u1;
      pk[s4][1] = (u2 >> 16) | u3;
    }
    sum += __shfl_xor(sum, 16);
    sum += __shfl_xor(sum, 32);
    lsum += sum;
    // channel shuffles (src pushes uniform tile c; dest selects c = 2ks+(quad>>1))
    const int src0 = ((quad & 1) * 2) * 16 + l16;
    const int src1 = src0 + 16;
    unsigned sh[4][4];
#pragma unroll
    for (int c = 0; c < 4; ++c) {
      sh[c][0] = (unsigned)__shfl((int)pk[c][0], src0);
      sh[c][1] = (unsigned)__shfl((int)pk[c][1], src0);
      sh[c][2] = (unsigned)__shfl((int)pk[c][0], src1);
      sh[c][3] = (unsigned)__shfl((int)pk[c][1], src1);
    }
    const bool hi = (quad >> 1) != 0;
    bf16x8 pb[2];
#pragma unroll
    for (int ks2 = 0; ks2 < 2; ++ks2) {
      union { unsigned u[4]; bf16x8 bv; } cv;
#pragma unroll
      for (int w = 0; w < 4; ++w)
        cv.u[w] = hi ? sh[2 * ks2 + 1][w] : sh[2 * ks2][w];
      pb[ks2] = cv.bv;
    }
    __builtin_amdgcn_s_setprio(1);
#pragma unroll
    for (int dt = 0; dt < 8; ++dt) {
      int row = dt * 16 + l16;
#pragma unroll
      for (int ks2 = 0; ks2 < 2; ++ks2) {
        bf16x8 a = ld_frag(&vsb[row * 64 + (((ks2 * 4 + quad) ^ (row & 7)) << 3)]);
        accO[dt] = __builtin_amdgcn_mfma_f32_16x16x32_bf16(a, pb[ks2], accO[dt], 0, 0, 0);
      }
    }
    __builtin_amdgcn_s_setprio(0);
    __syncthreads();   // implicit vmcnt(0): prefetch landed; all reads of buf[cur] done
    cur ^= 1;
  }
  float rl = 1.f / lsum;
  const size_t orow = ((size_t)(qt * 64 + wave * 16 + l16)) * NQD + h * HD;
#pragma unroll
  for (int dt = 0; dt < 8; ++dt) {
    unsigned w0 = (unsigned)f2bf(accO[dt][0] * rl) | ((unsigned)f2bf(accO[dt][1] * rl) << 16);
    unsigned w1 = (unsigned)f2bf(accO[dt][2] * rl) | ((unsigned)f2bf(accO[dt][3] * rl) << 16);
    *(unsigned*)&O[orow + dt * 16 + quad * 4] = w0;
    *(unsigned*)&O[orow + dt * 16 + quad * 4 + 2] = w1;
  }
}

extern "C" void kernel_launch(void* const* d_in, const int* in_sizes, int n_in,
                              void* d_out, int out_size, void* d_ws, size_t ws_size,
                              hipStream_t stream) {
  const float* hidden = (const float*)d_in[0];
  const float* cosp = (const float*)d_in[1];
  const float* sinp = (const float*)d_in[2];
  const float* Wq = (const float*)d_in[3];
  const float* bq = (const float*)d_in[4];
  const float* Wk = (const float*)d_in[5];
  const float* bk = (const float*)d_in[6];
  const float* Wv = (const float*)d_in[7];
  const float* bv = (const float*)d_in[8];
  const float* Wo = (const float*)d_in[9];
  float* out = (float*)d_out;

  const size_t HID_N = (size_t)S_LEN * HDIM;
  const size_t WQ_N = (size_t)HDIM * NQD;
  const size_t KV_N = (size_t)S_LEN * NKVD;

  char* p = (char*)d_ws;
  size_t off = 0;
  auto take = [&](size_t bytes) {
    void* r = p + off; off += (bytes + 255) & ~(size_t)255; return r;
  };
  unsigned short* hid_bf = (unsigned short*)take(HID_N * 2);
  unsigned short* wqkvT = (unsigned short*)take((size_t)NQKV * HDIM * 2);
  unsigned short* woT = (unsigned short*)take(WQ_N * 2);
  float* bcat = (float*)take(NQKV * 4);
  float* cmT = (float*)take((size_t)HD * S_LEN * 4);
  float* smT = (float*)take((size_t)HD * S_LEN * 4);
  unsigned short* q_rot = (unsigned short*)take(HID_N * 2);
  unsigned short* k_rot = (unsigned short*)take(KV_N * 2);
  unsigned short* v_t = (unsigned short*)take(KV_N * 2);
  unsigned short* attn_bf = (unsigned short*)take(HID_N * 2);
  if (off > ws_size) return;   // loud failure: output stays poisoned

  cvt_kernel<<<(int)((HID_N / 4 + 255) / 256), 256, 0, stream>>>(hidden, hid_bf, (int)(HID_N / 4));
  dim3 tb(32, 8);
  tcvt<<<dim3(NQD / 32, HDIM / 32), tb, 0, stream>>>(Wq, wqkvT, HDIM, NQD, NQD);
  tcvt<<<dim3(NKVD / 32, HDIM / 32), tb, 0, stream>>>(Wk, wqkvT + (size_t)NQD * HDIM, HDIM, NKVD, NKVD);
  tcvt<<<dim3(NKVD / 32, HDIM / 32), tb, 0, stream>>>(Wv, wqkvT + (size_t)(NQD + NKVD) * HDIM, HDIM, NKVD, NKVD);
  tcvt<<<dim3(NQD / 32, NQD / 32), tb, 0, stream>>>(Wo, woT, NQD, NQD, NQD);
  biascat<<<(NQKV + 255) / 256, 256, 0, stream>>>(bq, bk, bv, bcat);
  mrope_build<<<dim3(S_LEN / 256, HD), 256, 0, stream>>>(cosp, sinp, cmT, smT);

  // fused QKV projection + rope + head-major/transposed stores
  gemm_k64<1><<<dim3(NQKV / 128, S_LEN / 128), 256, 0, stream>>>(
      hid_bf, wqkvT, bcat, cmT, smT, nullptr, q_rot, k_rot, v_t, S_LEN, NQKV, HDIM);
  // attention
  attn2<<<NH * (S_LEN / 64), 256, 0, stream>>>(q_rot, k_rot, v_t, attn_bf);
  // output projection
  gemm_k64<0><<<dim3(NQD / 128, S_LEN / 128), 256, 0, stream>>>(
      attn_bf, woT, nullptr, nullptr, nullptr, out, nullptr, nullptr, nullptr,
      S_LEN, NQD, NQD);
}

// Round 3
// 443.734 us; speedup vs baseline: 1.2345x; 1.0831x over previous
//
#include <hip/hip_runtime.h>
#include <hip/hip_bf16.h>

#define S_LEN 2048
#define HDIM 3584
#define NH 28
#define NKV 4
#define HD 128
#define NQD 3584   // NH*HD
#define NKVD 512   // NKV*HD
#define NQKV 4608  // NQD + 2*NKVD

typedef __bf16 bf16x8 __attribute__((ext_vector_type(8)));
typedef float f32x4 __attribute__((ext_vector_type(4)));
typedef unsigned short u16x8 __attribute__((ext_vector_type(8)));

__device__ __forceinline__ unsigned short f2bf(float f) {
  unsigned u = __builtin_bit_cast(unsigned, f);
  u += 0x7fffu + ((u >> 16) & 1u);   // RNE
  return (unsigned short)(u >> 16);
}

__device__ __forceinline__ bf16x8 ld_frag(const unsigned short* p) {
  union { u16x8 u; bf16x8 b; } cv;
  cv.u = *(const u16x8*)p;   // 16B ds_read_b128
  return cv.b;
}

// async global->LDS, 16B per lane; lds dest is wave-uniform base + lane*16
__device__ __forceinline__ void async_cp16(const void* g, void* lds) {
  __builtin_amdgcn_global_load_lds(
      (const __attribute__((address_space(1))) unsigned int*)g,
      (__attribute__((address_space(3))) unsigned int*)lds, 16, 0, 0);
}

// ---------------- fp32 -> bf16 flat convert ----------------
__global__ __launch_bounds__(256) void cvt_kernel(const float* __restrict__ in,
                                                  unsigned short* __restrict__ out, int n4) {
  int i = blockIdx.x * 256 + threadIdx.x;
  if (i >= n4) return;
  float4 v = ((const float4*)in)[i];
  ushort4 o;
  o.x = f2bf(v.x); o.y = f2bf(v.y); o.z = f2bf(v.z); o.w = f2bf(v.w);
  ((ushort4*)out)[i] = o;
}

// ---------------- tiled transpose + fp32->bf16: out[c][r] = in[r][c] ----------------
__global__ __launch_bounds__(256) void tcvt(const float* __restrict__ in,
                                            unsigned short* __restrict__ out,
                                            int R, int C, int ldin) {
  __shared__ float t[32][33];
  const int tx = threadIdx.x, ty = threadIdx.y;   // 32 x 8
  const int r0 = blockIdx.y * 32, c0 = blockIdx.x * 32;
#pragma unroll
  for (int j = 0; j < 4; ++j)
    t[ty + 8 * j][tx] = in[(size_t)(r0 + ty + 8 * j) * ldin + c0 + tx];
  __syncthreads();
#pragma unroll
  for (int j = 0; j < 4; ++j)
    out[(size_t)(c0 + ty + 8 * j) * R + r0 + tx] = f2bf(t[tx][ty + 8 * j]);
}

// ---------------- concat bias [bq | bk | bv] ----------------
__global__ void biascat(const float* __restrict__ bq, const float* __restrict__ bk,
                        const float* __restrict__ bv, float* __restrict__ o) {
  int i = blockIdx.x * 256 + threadIdx.x;
  if (i < NQD) o[i] = bq[i];
  else if (i < NQD + NKVD) o[i] = bk[i - NQD];
  else if (i < NQKV) o[i] = bv[i - NQD - NKVD];
}

// ---------------- build mrope'd cos/sin, transposed: cmT[d][s] ----------------
// sections: [0,16)=0 [16,40)=1 [40,64)=2 [64,80)=0 [80,104)=1 [104,128)=2
__global__ void mrope_build(const float* __restrict__ cosp, const float* __restrict__ sinp,
                            float* __restrict__ cmT, float* __restrict__ smT) {
  const int d = blockIdx.y;
  const int s = blockIdx.x * 256 + threadIdx.x;
  const int sec = d < 16 ? 0 : d < 40 ? 1 : d < 64 ? 2 : d < 80 ? 0 : d < 104 ? 1 : 2;
  const size_t src = ((size_t)sec * S_LEN + s) * HD + d;
  cmT[(size_t)d * S_LEN + s] = cosp[src];
  smT[(size_t)d * S_LEN + s] = sinp[src];
}

// ---------------- 128x128 bf16 GEMM, BK=64, global_load_lds staging ----------------
// Wave owns rows [wrow, wrow+64) and cols {wc2+0..31} U {wc2+64..95} (closed under ^64
// so the rope partner d^64 is register j^2 in the same lane).
// LDS chunk swizzle: position (row,p) holds logical k-chunk p^(row&7) -> 2-way max.
// v2: double-buffered LDS, prefetch tile k+1 before computing tile k — one barrier
// per K-step, vmcnt(0) drain lands after the MFMA cluster instead of before it.
// MODE 0: fp32 C out (+bias). MODE 1: fused QKV epilogue (rope q/k, transpose-cast v).
#define QSCALE (0.08838834764831845f * 1.4426950408889634f)
template <int MODE>
__global__ __launch_bounds__(256) void gemm_k64(
    const unsigned short* __restrict__ A,   // [M][K] bf16
    const unsigned short* __restrict__ Bt,  // [N][K] bf16
    const float* __restrict__ bias,         // [N] or null
    const float* __restrict__ cmT,          // [HD][S] (MODE 1)
    const float* __restrict__ smT,
    float* __restrict__ Cout,               // MODE 0
    unsigned short* __restrict__ qr,        // MODE 1: [NH][S][HD]
    unsigned short* __restrict__ kr,        // MODE 1: [NKV][S][HD]
    unsigned short* __restrict__ vt,        // MODE 1: [NKVD][S]
    int M, int N, int K) {
  __shared__ __align__(16) unsigned short As[2][128 * 64];
  __shared__ __align__(16) unsigned short Bs[2][128 * 64];
  const int tid = threadIdx.x, wave = tid >> 6;
  const int lane = tid & 63, quad = lane >> 4, l16 = lane & 15;
  const int bm = blockIdx.y * 128, bn = blockIdx.x * 128;
  const int wrow = (wave >> 1) * 64, wc2 = (wave & 1) * 32;
  f32x4 acc[4][4] = {};

  auto stage = [&](int bsel, int k0) {
#pragma unroll
    for (int t = 0; t < 4; ++t) {
      int g = t * 256 + tid;                 // chunk 0..1023
      int row = g >> 3;
      int c = (g & 7) ^ (row & 7);           // logical k-chunk to fetch
      async_cp16(&A[(size_t)(bm + row) * K + k0 + c * 8], &As[bsel][(size_t)g * 8]);
      async_cp16(&Bt[(size_t)(bn + row) * K + k0 + c * 8], &Bs[bsel][(size_t)g * 8]);
    }
  };

  stage(0, 0);
  __syncthreads();             // implicit vmcnt(0): tile 0 landed
  int cur = 0;
  for (int k0 = 0; k0 < K; k0 += 64) {
    if (k0 + 64 < K) stage(cur ^ 1, k0 + 64);   // prefetch next K-tile
    const unsigned short* as = As[cur];
    const unsigned short* bs = Bs[cur];
    bf16x8 af[4][2], bfr[4][2];
#pragma unroll
    for (int i = 0; i < 4; ++i) {
      int ra = wrow + i * 16 + l16;
#pragma unroll
      for (int ks = 0; ks < 2; ++ks)
        af[i][ks] = ld_frag(&as[ra * 64 + (((ks * 4 + quad) ^ (ra & 7)) << 3)]);
    }
#pragma unroll
    for (int j = 0; j < 4; ++j) {
      int rb = wc2 + (j & 1) * 16 + (j >> 1) * 64 + l16;
#pragma unroll
      for (int ks = 0; ks < 2; ++ks)
        bfr[j][ks] = ld_frag(&bs[rb * 64 + (((ks * 4 + quad) ^ (rb & 7)) << 3)]);
    }
    __builtin_amdgcn_s_setprio(1);
#pragma unroll
    for (int ks = 0; ks < 2; ++ks)
#pragma unroll
      for (int i = 0; i < 4; ++i)
#pragma unroll
        for (int j = 0; j < 4; ++j)
          acc[i][j] = __builtin_amdgcn_mfma_f32_16x16x32_bf16(af[i][ks], bfr[j][ks],
                                                              acc[i][j], 0, 0, 0);
    __builtin_amdgcn_s_setprio(0);
    __syncthreads();   // implicit vmcnt(0): prefetch landed; reads of buf[cur] retired
    cur ^= 1;
  }
  int dcol[4];
  float bj[4];
#pragma unroll
  for (int j = 0; j < 4; ++j) {
    dcol[j] = wc2 + (j & 1) * 16 + (j >> 1) * 64 + l16;
    bj[j] = bias ? bias[bn + dcol[j]] : 0.f;
  }
  if (MODE == 0) {
#pragma unroll
    for (int i = 0; i < 4; ++i) {
      int row0 = bm + wrow + i * 16 + quad * 4;
#pragma unroll
      for (int j = 0; j < 4; ++j)
#pragma unroll
        for (int r = 0; r < 4; ++r)
          Cout[(size_t)(row0 + r) * N + bn + dcol[j]] = acc[i][j][r] + bj[j];
    }
  } else {
    const int tile = blockIdx.x;  // 0..27 q head | 28..31 k head | 32..35 v head
    if (tile < 32) {
      const bool isq = tile < 28;
      unsigned short* dst = isq ? (qr + (size_t)tile * S_LEN * HD)
                                : (kr + (size_t)(tile - 28) * S_LEN * HD);
      const float scl = isq ? QSCALE : 1.0f;
#pragma unroll
      for (int i = 0; i < 4; ++i) {
        int srow = bm + wrow + i * 16 + quad * 4;
#pragma unroll
        for (int j = 0; j < 4; ++j) {
          int d = dcol[j];
          f32x4 cm4 = *(const f32x4*)&cmT[(size_t)d * S_LEN + srow];
          f32x4 sm4 = *(const f32x4*)&smT[(size_t)d * S_LEN + srow];
#pragma unroll
          for (int r = 0; r < 4; ++r) {
            float x = acc[i][j][r] + bj[j];
            float px = acc[i][j ^ 2][r] + bj[j ^ 2];
            float pr = (j < 2) ? -px : px;   // rotate_half partner (d^64, same lane)
            dst[(size_t)(srow + r) * HD + d] = f2bf((x * cm4[r] + pr * sm4[r]) * scl);
          }
        }
      }
    } else {
      const int kvh = tile - 32;
#pragma unroll
      for (int i = 0; i < 4; ++i) {
        int srow = bm + wrow + i * 16 + quad * 4;
#pragma unroll
        for (int j = 0; j < 4; ++j) {
          int d = dcol[j];
          unsigned w0 = (unsigned)f2bf(acc[i][j][0] + bj[j]) |
                        ((unsigned)f2bf(acc[i][j][1] + bj[j]) << 16);
          unsigned w1 = (unsigned)f2bf(acc[i][j][2] + bj[j]) |
                        ((unsigned)f2bf(acc[i][j][3] + bj[j]) << 16);
          unsigned short* vp = &vt[(size_t)(kvh * HD + d) * S_LEN + srow];
          *(unsigned*)vp = w0;
          *(unsigned*)(vp + 2) = w1;
        }
      }
    }
  }
}

// ---------------- flash attention, S^T formulation, tile-0 max ----------------
// block = (head, 128 q rows); 8 waves x 16-q strips, 512 threads. Q in registers
// (B-operand). S^T = K.Q^T : C col=l16=q, row=quad*4+r=sk_local. Tile-0 row max
// (scores bounded; overflow would be inf -> loud fail). P truncated to bf16 (RTZ);
// lsum sums the SAME truncated values so num/denom errors cancel. No accO rescale.
// v3: 8-wave block — K/V LDS tiles (64KB dbuf) shared by 2x the q-rows, so
// 2 blocks/CU = 16 waves/CU (was 6): TLP to hide exp2f/shuffle latency.
// Double-buffered K/V staging; one barrier per iter; setprio around MFMA.
__global__ __launch_bounds__(512, 4) void attn2(
    const unsigned short* __restrict__ Q,   // [NH][S][HD] bf16, pre-scaled by QSCALE
    const unsigned short* __restrict__ Kh,  // [NKV][S][HD] bf16
    const unsigned short* __restrict__ Vt,  // [NKVD][S] bf16 (d-major)
    unsigned short* __restrict__ O) {       // [S][NQD] bf16
  __shared__ __align__(16) unsigned short Ks[2][64 * 128];
  __shared__ __align__(16) unsigned short Vs[2][128 * 64];
  const int tid = threadIdx.x, wave = tid >> 6, lane = tid & 63;
  const int quad = lane >> 4, l16 = lane & 15;
  const int b = blockIdx.x;
  const int xcd = b & 7, slot = b >> 3;        // 448 blocks: 56 per xcd
  const int kvh = xcd & 3;
  const int strip = (xcd >> 2) * 56 + slot;    // 0..111 within kvh
  const int h = kvh * 7 + (strip >> 4);
  const int qt = strip & 15;                   // 128-row q tile

  const unsigned short* Kbase = Kh + (size_t)kvh * S_LEN * HD;
  const unsigned short* Vbase = Vt + (size_t)kvh * HD * S_LEN;

  auto stage = [&](int bsel, int kt) {
#pragma unroll
    for (int t = 0; t < 2; ++t) {
      int g = (wave * 2 + t) * 64 + lane;      // 1024 chunks over 512 threads
      int krow = g >> 4, kq = ((g & 15) ^ (krow & 15)) * 8;
      async_cp16(&Kbase[(size_t)(kt * 64 + krow) * HD + kq], &Ks[bsel][(size_t)g * 8]);
      int vrow = g >> 3, vc = ((g & 7) ^ (vrow & 7)) * 8;
      async_cp16(&Vbase[(size_t)vrow * S_LEN + kt * 64 + vc], &Vs[bsel][(size_t)g * 8]);
    }
  };

  stage(0, 0);                 // tile 0 in flight while Q fragments load
  bf16x8 qf[4];
  const size_t qrow = ((size_t)h * S_LEN + qt * 128 + wave * 16 + l16) * HD;
#pragma unroll
  for (int kc = 0; kc < 4; ++kc)
    qf[kc] = ld_frag(&Q[qrow + kc * 32 + quad * 8]);
  f32x4 accO[8] = {};
  float m = 0.f, lsum = 0.f;
  __syncthreads();             // implicit vmcnt(0): tile 0 landed
  int cur = 0;
  for (int kt = 0; kt < S_LEN / 64; ++kt) {
    if (kt + 1 < S_LEN / 64) stage(cur ^ 1, kt + 1);   // prefetch next tile
    const unsigned short* ksb = Ks[cur];
    const unsigned short* vsb = Vs[cur];
    f32x4 st[4] = {};
    __builtin_amdgcn_s_setprio(1);
#pragma unroll
    for (int s4 = 0; s4 < 4; ++s4) {
      int row = s4 * 16 + l16;
#pragma unroll
      for (int kc = 0; kc < 4; ++kc) {
        bf16x8 a = ld_frag(&ksb[row * 128 + (((kc * 4 + quad) ^ (row & 15)) << 3)]);
        st[s4] = __builtin_amdgcn_mfma_f32_16x16x32_bf16(a, qf[kc], st[s4], 0, 0, 0);
      }
    }
    __builtin_amdgcn_s_setprio(0);
    if (kt == 0) {   // per-q-row max of tile 0; never updated (scores bounded)
      float mt = st[0][0];
#pragma unroll
      for (int s4 = 0; s4 < 4; ++s4)
#pragma unroll
        for (int r = 0; r < 4; ++r) mt = fmaxf(mt, st[s4][r]);
      mt = fmaxf(mt, __shfl_xor(mt, 16));
      mt = fmaxf(mt, __shfl_xor(mt, 32));
      m = mt;
    }
    float sum = 0.f;
    unsigned pk[4][2];
#pragma unroll
    for (int s4 = 0; s4 < 4; ++s4) {
      unsigned u0 = __builtin_bit_cast(unsigned, exp2f(st[s4][0] - m)) & 0xffff0000u;
      unsigned u1 = __builtin_bit_cast(unsigned, exp2f(st[s4][1] - m)) & 0xffff0000u;
      unsigned u2 = __builtin_bit_cast(unsigned, exp2f(st[s4][2] - m)) & 0xffff0000u;
      unsigned u3 = __builtin_bit_cast(unsigned, exp2f(st[s4][3] - m)) & 0xffff0000u;
      sum += __builtin_bit_cast(float, u0) + __builtin_bit_cast(float, u1) +
             __builtin_bit_cast(float, u2) + __builtin_bit_cast(float, u3);
      pk[s4][0] = (u0 >> 16) | u1;
      pk[s4][1] = (u2 >> 16) | u3;
    }
    sum += __shfl_xor(sum, 16);
    sum += __shfl_xor(sum, 32);
    lsum += sum;
    // channel shuffles (src pushes uniform tile c; dest selects c = 2ks+(quad>>1))
    const int src0 = ((quad & 1) * 2) * 16 + l16;
    const int src1 = src0 + 16;
    unsigned sh[4][4];
#pragma unroll
    for (int c = 0; c < 4; ++c) {
      sh[c][0] = (unsigned)__shfl((int)pk[c][0], src0);
      sh[c][1] = (unsigned)__shfl((int)pk[c][1], src0);
      sh[c][2] = (unsigned)__shfl((int)pk[c][0], src1);
      sh[c][3] = (unsigned)__shfl((int)pk[c][1], src1);
    }
    const bool hi = (quad >> 1) != 0;
    bf16x8 pb[2];
#pragma unroll
    for (int ks2 = 0; ks2 < 2; ++ks2) {
      union { unsigned u[4]; bf16x8 bv; } cv;
#pragma unroll
      for (int w = 0; w < 4; ++w)
        cv.u[w] = hi ? sh[2 * ks2 + 1][w] : sh[2 * ks2][w];
      pb[ks2] = cv.bv;
    }
    __builtin_amdgcn_s_setprio(1);
#pragma unroll
    for (int dt = 0; dt < 8; ++dt) {
      int row = dt * 16 + l16;
#pragma unroll
      for (int ks2 = 0; ks2 < 2; ++ks2) {
        bf16x8 a = ld_frag(&vsb[row * 64 + (((ks2 * 4 + quad) ^ (row & 7)) << 3)]);
        accO[dt] = __builtin_amdgcn_mfma_f32_16x16x32_bf16(a, pb[ks2], accO[dt], 0, 0, 0);
      }
    }
    __builtin_amdgcn_s_setprio(0);
    __syncthreads();   // implicit vmcnt(0): prefetch landed; all reads of buf[cur] done
    cur ^= 1;
  }
  float rl = 1.f / lsum;
  const size_t orow = ((size_t)(qt * 128 + wave * 16 + l16)) * NQD + h * HD;
#pragma unroll
  for (int dt = 0; dt < 8; ++dt) {
    unsigned w0 = (unsigned)f2bf(accO[dt][0] * rl) | ((unsigned)f2bf(accO[dt][1] * rl) << 16);
    unsigned w1 = (unsigned)f2bf(accO[dt][2] * rl) | ((unsigned)f2bf(accO[dt][3] * rl) << 16);
    *(unsigned*)&O[orow + dt * 16 + quad * 4] = w0;
    *(unsigned*)&O[orow + dt * 16 + quad * 4 + 2] = w1;
  }
}

extern "C" void kernel_launch(void* const* d_in, const int* in_sizes, int n_in,
                              void* d_out, int out_size, void* d_ws, size_t ws_size,
                              hipStream_t stream) {
  const float* hidden = (const float*)d_in[0];
  const float* cosp = (const float*)d_in[1];
  const float* sinp = (const float*)d_in[2];
  const float* Wq = (const float*)d_in[3];
  const float* bq = (const float*)d_in[4];
  const float* Wk = (const float*)d_in[5];
  const float* bk = (const float*)d_in[6];
  const float* Wv = (const float*)d_in[7];
  const float* bv = (const float*)d_in[8];
  const float* Wo = (const float*)d_in[9];
  float* out = (float*)d_out;

  const size_t HID_N = (size_t)S_LEN * HDIM;
  const size_t WQ_N = (size_t)HDIM * NQD;
  const size_t KV_N = (size_t)S_LEN * NKVD;

  char* p = (char*)d_ws;
  size_t off = 0;
  auto take = [&](size_t bytes) {
    void* r = p + off; off += (bytes + 255) & ~(size_t)255; return r;
  };
  unsigned short* hid_bf = (unsigned short*)take(HID_N * 2);
  unsigned short* wqkvT = (unsigned short*)take((size_t)NQKV * HDIM * 2);
  unsigned short* woT = (unsigned short*)take(WQ_N * 2);
  float* bcat = (float*)take(NQKV * 4);
  float* cmT = (float*)take((size_t)HD * S_LEN * 4);
  float* smT = (float*)take((size_t)HD * S_LEN * 4);
  unsigned short* q_rot = (unsigned short*)take(HID_N * 2);
  unsigned short* k_rot = (unsigned short*)take(KV_N * 2);
  unsigned short* v_t = (unsigned short*)take(KV_N * 2);
  unsigned short* attn_bf = (unsigned short*)take(HID_N * 2);
  if (off > ws_size) return;   // loud failure: output stays poisoned

  cvt_kernel<<<(int)((HID_N / 4 + 255) / 256), 256, 0, stream>>>(hidden, hid_bf, (int)(HID_N / 4));
  dim3 tb(32, 8);
  tcvt<<<dim3(NQD / 32, HDIM / 32), tb, 0, stream>>>(Wq, wqkvT, HDIM, NQD, NQD);
  tcvt<<<dim3(NKVD / 32, HDIM / 32), tb, 0, stream>>>(Wk, wqkvT + (size_t)NQD * HDIM, HDIM, NKVD, NKVD);
  tcvt<<<dim3(NKVD / 32, HDIM / 32), tb, 0, stream>>>(Wv, wqkvT + (size_t)(NQD + NKVD) * HDIM, HDIM, NKVD, NKVD);
  tcvt<<<dim3(NQD / 32, NQD / 32), tb, 0, stream>>>(Wo, woT, NQD, NQD, NQD);
  biascat<<<(NQKV + 255) / 256, 256, 0, stream>>>(bq, bk, bv, bcat);
  mrope_build<<<dim3(S_LEN / 256, HD), 256, 0, stream>>>(cosp, sinp, cmT, smT);

  // fused QKV projection + rope + head-major/transposed stores
  gemm_k64<1><<<dim3(NQKV / 128, S_LEN / 128), 256, 0, stream>>>(
      hid_bf, wqkvT, bcat, cmT, smT, nullptr, q_rot, k_rot, v_t, S_LEN, NQKV, HDIM);
  // attention: 28 heads x 16 q-tiles of 128 rows, 512-thread blocks
  attn2<<<NH * (S_LEN / 128), 512, 0, stream>>>(q_rot, k_rot, v_t, attn_bf);
  // output projection
  gemm_k64<0><<<dim3(NQD / 128, S_LEN / 128), 256, 0, stream>>>(
      attn_bf, woT, nullptr, nullptr, nullptr, out, nullptr, nullptr, nullptr,
      S_LEN, NQD, NQD);
}